// Round 4
// baseline (108.413 us; speedup 1.0000x reference)
//
#include <hip/hip_runtime.h>
#include <cfloat>
#include <cmath>

// Problem constants (match reference)
#define IC 480        // IN_CHANNELS
#define OC 18         // OUT_CHANNELS
#define HH 256
#define WW 256
#define HW_ 65536     // H*W
#define NPROP 30      // MAX_PROPOSALS
#define CG 4          // channel groups for the dot-product kernel
#define CPG 120       // channels per group (480/4)
#define CAP 6144      // candidate capacity (expected survivors ~2600)

// Output layout (14520 floats):
//   [0,60)        instance_coord (30,2)  row-major (y,x)
//   [60,90)       scores (30,)
//   [90,14490)    instance_param (480,30)  ROW-MAJOR CHANNELS-FIRST
//                 (features[0,:,y,x] puts the broadcast dim FIRST -> (30,480);
//                  .T -> (480,30))
//   [14490,14520) valid (30,)

// ---------------------------------------------------------------------------
// K1: partial dot products  partial[cg][p] = sum_{c in group} f[c,p]*w17[c]
// float2-vectorized over pixels; grid (128, 4) x 256 threads = 512 blocks.
// (Exact round-1 arithmetic — proven to match the reference's selection.)
// ---------------------------------------------------------------------------
__global__ __launch_bounds__(256) void k_dot(const float* __restrict__ f,
                                             const float* __restrict__ w,
                                             float* __restrict__ partial) {
    __shared__ float sw[CPG];
    const int tid = threadIdx.x;
    const int cg = blockIdx.y;
    const int c0 = cg * CPG;
    if (tid < CPG) sw[tid] = w[17 * IC + c0 + tid];
    __syncthreads();
    const int p2 = blockIdx.x * 256 + tid;            // float2 pair index [0,32768)
    const float2* __restrict__ f2 = (const float2*)f;
    float ax = 0.f, ay = 0.f;
    #pragma unroll 8
    for (int c = 0; c < CPG; ++c) {
        float2 v = f2[(size_t)(c0 + c) * (HW_ / 2) + p2];
        float wc = sw[c];
        ax = fmaf(v.x, wc, ax);
        ay = fmaf(v.y, wc, ay);
    }
    float2 r; r.x = ax; r.y = ay;
    ((float2*)partial)[(size_t)cg * (HW_ / 2) + p2] = r;
}

// ---------------------------------------------------------------------------
// K2: fused  center = clip(sigmoid(sum+b));  c2 = (center + avg3(center))/2;
//     NMS: survivor iff c2 == max5(c2).  Survivors appended to candidate list.
// Tile 32x8 output per 256-thread block, halo 3 for center, halo 2 for c2.
// avg pool: SAME zero-pad sum, ALWAYS /9; max pool: SAME -inf pad.
// ---------------------------------------------------------------------------
__global__ __launch_bounds__(256) void k_pool(const float* __restrict__ partial,
                                              const float* __restrict__ conv_b,
                                              float* __restrict__ cand_val,
                                              int* __restrict__ cand_idx,
                                              int* __restrict__ counter) {
    const int TX = 32, TY = 8;
    __shared__ float sc[TY + 6][TX + 6];   // center, halo 3
    __shared__ float s2[TY + 4][TX + 4];   // c2, halo 2
    const int tid = threadIdx.x;
    const int ox = blockIdx.x * TX, oy = blockIdx.y * TY;
    const float b = conv_b[OC - 1];

    for (int i = tid; i < (TY + 6) * (TX + 6); i += 256) {
        int ly = i / (TX + 6), lx = i % (TX + 6);
        int gy = oy - 3 + ly, gx = ox - 3 + lx;
        float v = 0.f;                                   // zero pad for avg-sum
        if (gy >= 0 && gy < HH && gx >= 0 && gx < WW) {
            int p = gy * WW + gx;
            float raw = partial[p] + partial[HW_ + p] + partial[2 * HW_ + p]
                      + partial[3 * HW_ + p] + b;
            float s = 1.f / (1.f + expf(-raw));
            v = fminf(fmaxf(s, 1e-4f), 1.f - 1e-4f);
        }
        sc[ly][lx] = v;
    }
    __syncthreads();

    for (int i = tid; i < (TY + 4) * (TX + 4); i += 256) {
        int ly = i / (TX + 4), lx = i % (TX + 4);
        int gy = oy - 2 + ly, gx = ox - 2 + lx;
        float v = -FLT_MAX;                              // -inf pad for max
        if (gy >= 0 && gy < HH && gx >= 0 && gx < WW) {
            float sum = 0.f;
            #pragma unroll
            for (int dy = 0; dy < 3; ++dy)
                #pragma unroll
                for (int dx = 0; dx < 3; ++dx)
                    sum += sc[ly + dy][lx + dx];
            v = (sc[ly + 1][lx + 1] + sum / 9.0f) * 0.5f;
        }
        s2[ly][lx] = v;
    }
    __syncthreads();

    const int tx = tid & 31, ty = tid >> 5;
    float c = s2[ty + 2][tx + 2];
    float m = -FLT_MAX;
    #pragma unroll
    for (int dy = 0; dy < 5; ++dy)
        #pragma unroll
        for (int dx = 0; dx < 5; ++dx)
            m = fmaxf(m, s2[ty + dy][tx + dx]);
    if (m == c) {                                        // survivor (c > 0 always)
        int slot = atomicAdd(counter, 1);
        if (slot < CAP) {
            cand_val[slot] = c;
            cand_idx[slot] = (oy + ty) * WW + (ox + tx);
        }
    }
}

// ---------------------------------------------------------------------------
// K3: single-block top-30 selection (descending, ties -> lower pixel index,
// matching lax.top_k) + write coords/scores/valid and selected pixel list.
// ---------------------------------------------------------------------------
__global__ __launch_bounds__(256) void k_select(const float* __restrict__ cand_val,
                                                const int* __restrict__ cand_idx,
                                                const int* __restrict__ counter,
                                                float* __restrict__ out,
                                                int* __restrict__ selpix) {
    __shared__ float lv[CAP];
    __shared__ int li[CAP];
    __shared__ float wrv[4]; __shared__ int wrp[4]; __shared__ int wrs[4];
    __shared__ float sval[NPROP]; __shared__ int spix[NPROP];
    const int tid = threadIdx.x;
    int n = *counter; if (n > CAP) n = CAP;
    for (int i = tid; i < n; i += 256) { lv[i] = cand_val[i]; li[i] = cand_idx[i]; }
    __syncthreads();

    for (int it = 0; it < NPROP; ++it) {
        float bv = -1.f; int bp = 0x7fffffff; int bs = -1;
        for (int j = tid; j < n; j += 256) {
            float v = lv[j]; int p = li[j];
            if (v > bv || (v == bv && p < bp)) { bv = v; bp = p; bs = j; }
        }
        #pragma unroll
        for (int off = 32; off > 0; off >>= 1) {
            float ov = __shfl_xor(bv, off);
            int   op = __shfl_xor(bp, off);
            int   os = __shfl_xor(bs, off);
            if (ov > bv || (ov == bv && op < bp)) { bv = ov; bp = op; bs = os; }
        }
        const int wid = tid >> 6;
        if ((tid & 63) == 0) { wrv[wid] = bv; wrp[wid] = bp; wrs[wid] = bs; }
        __syncthreads();
        if (tid == 0) {
            float fv = wrv[0]; int fp = wrp[0]; int fs = wrs[0];
            for (int wv = 1; wv < 4; ++wv)
                if (wrv[wv] > fv || (wrv[wv] == fv && wrp[wv] < fp)) {
                    fv = wrv[wv]; fp = wrp[wv]; fs = wrs[wv];
                }
            if (fs >= 0) { sval[it] = fv; spix[it] = fp; lv[fs] = -2.f; }
            else         { sval[it] = 0.f; spix[it] = 0; }
        }
        __syncthreads();
    }

    if (tid < NPROP) {
        int p = spix[tid];
        float s = sval[tid];
        out[2 * tid]     = (float)(p >> 8);   // y = p / 256
        out[2 * tid + 1] = (float)(p & 255);  // x = p % 256
        out[60 + tid] = s;                                     // scores
        out[60 + NPROP + NPROP * IC + tid] = (s > 0.01f) ? 1.f : 0.f;  // valid
        selpix[tid] = p;
    }
}

// ---------------------------------------------------------------------------
// K4: gather instance_param in (480, 30) layout:
//   out[90 + c*30 + i] = features[c, p_i]
// ---------------------------------------------------------------------------
__global__ __launch_bounds__(256) void k_gather(const float* __restrict__ f,
                                                const int* __restrict__ selpix,
                                                float* __restrict__ out) {
    __shared__ int sp[NPROP];
    const int tid = threadIdx.x;
    if (tid < NPROP) sp[tid] = selpix[tid];
    __syncthreads();
    int idx = blockIdx.x * 256 + tid;                 // 0 .. 14399
    if (idx < IC * NPROP) {
        int c = idx / NPROP, i = idx % NPROP;
        out[60 + NPROP + idx] = f[(size_t)c * HW_ + sp[i]];
    }
}

extern "C" void kernel_launch(void* const* d_in, const int* in_sizes, int n_in,
                              void* d_out, int out_size, void* d_ws, size_t ws_size,
                              hipStream_t stream) {
    const float* features = (const float*)d_in[0];
    const float* conv_w   = (const float*)d_in[1];
    const float* conv_b   = (const float*)d_in[2];
    float* out = (float*)d_out;
    char* ws = (char*)d_ws;

    // ws layout (~1.05 MB total)
    float* partial  = (float*)ws;                               // 4*65536*4 = 1 MB
    float* cand_val = (float*)(ws + (1 << 20));                 // 24 KB
    int*   cand_idx = (int*)  (ws + (1 << 20) + CAP * 4);       // 24 KB
    int*   counter  = (int*)  (ws + (1 << 20) + CAP * 8);       // 4 B
    int*   selpix   = (int*)  (ws + (1 << 20) + CAP * 8 + 16);  // 120 B

    hipMemsetAsync(counter, 0, sizeof(int), stream);
    k_dot   <<<dim3(HW_ / 512, CG), 256, 0, stream>>>(features, conv_w, partial);
    k_pool  <<<dim3(WW / 32, HH / 8), 256, 0, stream>>>(partial, conv_b,
                                                        cand_val, cand_idx, counter);
    k_select<<<1, 256, 0, stream>>>(cand_val, cand_idx, counter, out, selpix);
    k_gather<<<(IC * NPROP + 255) / 256, 256, 0, stream>>>(features, selpix, out);
}

// Round 5
// 58.655 us; speedup vs baseline: 1.8483x; 1.8483x over previous
//
#include <hip/hip_runtime.h>
#include <cfloat>
#include <cmath>

// Problem constants (match reference)
#define IC 480        // IN_CHANNELS
#define OC 18         // OUT_CHANNELS
#define HH 256
#define WW 256
#define HW_ 65536     // H*W
#define NPROP 30      // MAX_PROPOSALS
#define CG 8          // channel groups for the dot-product kernel
#define CPG 60        // channels per group (480/8)
#define CAP 6144      // candidate capacity (expected survivors ~2600)

// Output layout (14520 floats):
//   [0,60)        instance_coord (30,2) (y,x)
//   [60,90)       scores (30,)
//   [90,14490)    instance_param (480,30)  channels-major (features[0,:,y,x].T)
//   [14490,14520) valid (30,)

// ---------------------------------------------------------------------------
// K1: partial dot products  partial[cg][p] = sum_{c in group} f[c,p]*w17[c]
// float2 loads; grid (128, 8) x 256 = 1024 blocks -> 4 blocks/CU.
// (Selection proven robust to accumulation regrouping: f32-grouped/f64/seq-f32
//  all produced the identical top-30.)
// ---------------------------------------------------------------------------
__global__ __launch_bounds__(256) void k_dot(const float* __restrict__ f,
                                             const float* __restrict__ w,
                                             float* __restrict__ partial) {
    __shared__ float sw[CPG];
    const int tid = threadIdx.x;
    const int cg = blockIdx.y;
    const int c0 = cg * CPG;
    if (tid < CPG) sw[tid] = w[17 * IC + c0 + tid];
    __syncthreads();
    const int p2 = blockIdx.x * 256 + tid;            // float2 pair index [0,32768)
    const float2* __restrict__ f2 = (const float2*)f;
    float ax = 0.f, ay = 0.f;
    #pragma unroll 12
    for (int c = 0; c < CPG; ++c) {
        float2 v = f2[(size_t)(c0 + c) * (HW_ / 2) + p2];
        float wc = sw[c];
        ax = fmaf(v.x, wc, ax);
        ay = fmaf(v.y, wc, ay);
    }
    float2 r; r.x = ax; r.y = ay;
    ((float2*)partial)[(size_t)cg * (HW_ / 2) + p2] = r;
}

// ---------------------------------------------------------------------------
// K2: fused  center = clip(sigmoid(sum+b));  c2 = (center + avg3(center))/2;
//     NMS: survivor iff c2 == max5(c2) -> atomic append to candidate list.
// ---------------------------------------------------------------------------
__global__ __launch_bounds__(256) void k_pool(const float* __restrict__ partial,
                                              const float* __restrict__ conv_b,
                                              float* __restrict__ cand_val,
                                              int* __restrict__ cand_idx,
                                              int* __restrict__ counter) {
    const int TX = 32, TY = 8;
    __shared__ float sc[TY + 6][TX + 6];   // center, halo 3
    __shared__ float s2[TY + 4][TX + 4];   // c2, halo 2
    const int tid = threadIdx.x;
    const int ox = blockIdx.x * TX, oy = blockIdx.y * TY;
    const float b = conv_b[OC - 1];

    for (int i = tid; i < (TY + 6) * (TX + 6); i += 256) {
        int ly = i / (TX + 6), lx = i % (TX + 6);
        int gy = oy - 3 + ly, gx = ox - 3 + lx;
        float v = 0.f;                                   // zero pad for avg-sum
        if (gy >= 0 && gy < HH && gx >= 0 && gx < WW) {
            int p = gy * WW + gx;
            float raw = b;
            #pragma unroll
            for (int g = 0; g < CG; ++g) raw += partial[g * HW_ + p];
            float s = 1.f / (1.f + expf(-raw));
            v = fminf(fmaxf(s, 1e-4f), 1.f - 1e-4f);
        }
        sc[ly][lx] = v;
    }
    __syncthreads();

    for (int i = tid; i < (TY + 4) * (TX + 4); i += 256) {
        int ly = i / (TX + 4), lx = i % (TX + 4);
        int gy = oy - 2 + ly, gx = ox - 2 + lx;
        float v = -FLT_MAX;                              // -inf pad for max
        if (gy >= 0 && gy < HH && gx >= 0 && gx < WW) {
            float sum = 0.f;
            #pragma unroll
            for (int dy = 0; dy < 3; ++dy)
                #pragma unroll
                for (int dx = 0; dx < 3; ++dx)
                    sum += sc[ly + dy][lx + dx];
            v = (sc[ly + 1][lx + 1] + sum / 9.0f) * 0.5f;
        }
        s2[ly][lx] = v;
    }
    __syncthreads();

    const int tx = tid & 31, ty = tid >> 5;
    float c = s2[ty + 2][tx + 2];
    float m = -FLT_MAX;
    #pragma unroll
    for (int dy = 0; dy < 5; ++dy)
        #pragma unroll
        for (int dx = 0; dx < 5; ++dx)
            m = fmaxf(m, s2[ty + dy][tx + dx]);
    if (m == c) {                                        // survivor (c > 0 always)
        int slot = atomicAdd(counter, 1);
        if (slot < CAP) {
            cand_val[slot] = c;
            cand_idx[slot] = (oy + ty) * WW + (ox + tx);
        }
    }
}

// ---------------------------------------------------------------------------
// K3: wave-bitonic top-30.
// Key = (float_bits(value) << 32) | (0xFFFFFFFF - pixel): ascending u64 order
// == (value asc, then index desc) so reading from the top gives value desc
// with lower-index-first ties — exactly lax.top_k. Selection is a pure max
// over the candidate SET, so the atomic append order is irrelevant.
// 8 waves: each streams its 1/8 of candidates in 64-chunks, keeping a sorted
// top-64 via full bitonic sort (21 stages) + bitonic merge (6 stages).
// Cross-wave merge of the 8 sorted lists at the end.
// ---------------------------------------------------------------------------
__device__ __forceinline__ unsigned long long bsort64(unsigned long long key,
                                                      int lane) {
    #pragma unroll
    for (int k = 2; k <= 64; k <<= 1) {
        #pragma unroll
        for (int j = k >> 1; j > 0; j >>= 1) {
            unsigned long long o = __shfl_xor(key, j);
            bool lower = (lane & j) == 0;
            bool asc   = (lane & k) == 0;
            unsigned long long mn = key < o ? key : o;
            unsigned long long mx = key < o ? o : key;
            key = (lower == asc) ? mn : mx;
        }
    }
    return key;   // ascending across lanes
}

__device__ __forceinline__ unsigned long long bmerge64(unsigned long long key,
                                                       int lane) {
    #pragma unroll
    for (int j = 32; j > 0; j >>= 1) {
        unsigned long long o = __shfl_xor(key, j);
        bool lower = (lane & j) == 0;
        unsigned long long mn = key < o ? key : o;
        unsigned long long mx = key < o ? o : key;
        key = lower ? mn : mx;
    }
    return key;   // sorts a bitonic sequence ascending
}

__global__ __launch_bounds__(512) void k_select(const float* __restrict__ cand_val,
                                                const int* __restrict__ cand_idx,
                                                const int* __restrict__ counter,
                                                float* __restrict__ out,
                                                int* __restrict__ selpix) {
    __shared__ unsigned long long lk[512];
    const int tid = threadIdx.x;
    const int lane = tid & 63, wv = tid >> 6;
    int n = *counter; if (n > CAP) n = CAP;

    unsigned long long R = 0;   // all-zero list is trivially sorted ascending
    for (int base = wv * 64; base < n; base += 512) {
        int j = base + lane;
        unsigned long long key = 0;
        if (j < n) {
            unsigned fb = __float_as_uint(cand_val[j]);   // value>0 -> fb>0
            key = ((unsigned long long)fb << 32)
                | (unsigned long long)(0xFFFFFFFFu - (unsigned)cand_idx[j]);
        }
        key = bsort64(key, lane);                 // chunk ascending
        unsigned long long crev = __shfl_xor(key, 63);    // chunk descending
        R = R > crev ? R : crev;                  // top-64 of union (bitonic)
        R = bmerge64(R, lane);                    // re-sort ascending
    }
    lk[tid] = R;
    __syncthreads();

    if (wv == 0) {
        R = lk[lane];
        #pragma unroll
        for (int w = 1; w < 8; ++w) {
            unsigned long long c = lk[w * 64 + lane];
            unsigned long long crev = __shfl_xor(c, 63);
            R = R > crev ? R : crev;
            R = bmerge64(R, lane);
        }
        int r = 63 - lane;                        // rank r lives at lane 63-r
        if (r < NPROP) {
            float s = 0.f; int p = 0;
            if (R != 0) {
                s = __uint_as_float((unsigned)(R >> 32));
                p = (int)(0xFFFFFFFFu - (unsigned)(R & 0xFFFFFFFFu));
            }
            out[2 * r]     = (float)(p >> 8);     // y
            out[2 * r + 1] = (float)(p & 255);    // x
            out[60 + r] = s;                      // score
            out[60 + NPROP + NPROP * IC + r] = (s > 0.01f) ? 1.f : 0.f;  // valid
            selpix[r] = p;
        }
    }
}

// ---------------------------------------------------------------------------
// K4: gather instance_param in (480, 30) layout: out[90 + c*30 + i] = f[c, p_i]
// ---------------------------------------------------------------------------
__global__ __launch_bounds__(256) void k_gather(const float* __restrict__ f,
                                                const int* __restrict__ selpix,
                                                float* __restrict__ out) {
    __shared__ int sp[NPROP];
    const int tid = threadIdx.x;
    if (tid < NPROP) sp[tid] = selpix[tid];
    __syncthreads();
    int idx = blockIdx.x * 256 + tid;                 // 0 .. 14399
    if (idx < IC * NPROP) {
        int c = idx / NPROP, i = idx % NPROP;
        out[60 + NPROP + idx] = f[(size_t)c * HW_ + sp[i]];
    }
}

extern "C" void kernel_launch(void* const* d_in, const int* in_sizes, int n_in,
                              void* d_out, int out_size, void* d_ws, size_t ws_size,
                              hipStream_t stream) {
    const float* features = (const float*)d_in[0];
    const float* conv_w   = (const float*)d_in[1];
    const float* conv_b   = (const float*)d_in[2];
    float* out = (float*)d_out;
    char* ws = (char*)d_ws;

    // ws layout (~2.05 MB total)
    float* partial  = (float*)ws;                               // 8*65536*4 = 2 MB
    float* cand_val = (float*)(ws + (2 << 20));                 // 24 KB
    int*   cand_idx = (int*)  (ws + (2 << 20) + CAP * 4);       // 24 KB
    int*   counter  = (int*)  (ws + (2 << 20) + CAP * 8);       // 4 B
    int*   selpix   = (int*)  (ws + (2 << 20) + CAP * 8 + 16);  // 120 B

    hipMemsetAsync(counter, 0, sizeof(int), stream);
    k_dot   <<<dim3(HW_ / 512, CG), 256, 0, stream>>>(features, conv_w, partial);
    k_pool  <<<dim3(WW / 32, HH / 8), 256, 0, stream>>>(partial, conv_b,
                                                        cand_val, cand_idx, counter);
    k_select<<<1, 512, 0, stream>>>(cand_val, cand_idx, counter, out, selpix);
    k_gather<<<(IC * NPROP + 255) / 256, 256, 0, stream>>>(features, selpix, out);
}

// Round 6
// 54.817 us; speedup vs baseline: 1.9777x; 1.0700x over previous
//
#include <hip/hip_runtime.h>
#include <cfloat>
#include <cmath>

// Problem constants (match reference)
#define IC 480        // IN_CHANNELS
#define OC 18         // OUT_CHANNELS
#define HH 256
#define WW 256
#define HW_ 65536     // H*W
#define NPROP 30      // MAX_PROPOSALS
#define CG 8          // channel groups for the dot-product kernel
#define CPG 60        // channels per group (480/8)
#define CAP 6144      // candidate capacity (expected survivors ~2600)

// Output layout (14520 floats):
//   [0,60)        instance_coord (30,2) (y,x)
//   [60,90)       scores (30,)
//   [90,14490)    instance_param (480,30)  channels-major (features[0,:,y,x].T)
//   [14490,14520) valid (30,)

// ---------------------------------------------------------------------------
// K1: partial dot products  partial[cg][p] = sum_{c in group} f[c,p]*w17[c]
// float4 loads (16B/lane sweet spot, m13); grid (64, 8) x 256 = 512 blocks.
// Per-pixel accumulation chain identical to prior rounds (same CG grouping,
// same sequential fmaf order) -> bit-identical partials -> same selection.
// Block (0,0) also zeroes the candidate counter (consumed by k_pool, which
// only starts after this dispatch completes).
// ---------------------------------------------------------------------------
__global__ __launch_bounds__(256) void k_dot(const float* __restrict__ f,
                                             const float* __restrict__ w,
                                             float* __restrict__ partial,
                                             int* __restrict__ counter) {
    __shared__ float sw[CPG];
    const int tid = threadIdx.x;
    const int cg = blockIdx.y;
    const int c0 = cg * CPG;
    if (tid < CPG) sw[tid] = w[17 * IC + c0 + tid];
    if (blockIdx.x == 0 && cg == 0 && tid == 0) *counter = 0;
    __syncthreads();
    const int p4 = blockIdx.x * 256 + tid;            // float4 index [0,16384)
    const float4* __restrict__ f4 = (const float4*)f;
    float ax = 0.f, ay = 0.f, az = 0.f, aw = 0.f;
    #pragma unroll 10
    for (int c = 0; c < CPG; ++c) {
        float4 v = f4[(size_t)(c0 + c) * (HW_ / 4) + p4];
        float wc = sw[c];
        ax = fmaf(v.x, wc, ax);
        ay = fmaf(v.y, wc, ay);
        az = fmaf(v.z, wc, az);
        aw = fmaf(v.w, wc, aw);
    }
    float4 r; r.x = ax; r.y = ay; r.z = az; r.w = aw;
    ((float4*)partial)[(size_t)cg * (HW_ / 4) + p4] = r;
}

// ---------------------------------------------------------------------------
// K2: fused  center = clip(sigmoid(sum+b));  c2 = (center + avg3(center))/2;
//     NMS: survivor iff c2 == max5(c2) -> atomic append to candidate list.
// ---------------------------------------------------------------------------
__global__ __launch_bounds__(256) void k_pool(const float* __restrict__ partial,
                                              const float* __restrict__ conv_b,
                                              float* __restrict__ cand_val,
                                              int* __restrict__ cand_idx,
                                              int* __restrict__ counter) {
    const int TX = 32, TY = 8;
    __shared__ float sc[TY + 6][TX + 6];   // center, halo 3
    __shared__ float s2[TY + 4][TX + 4];   // c2, halo 2
    const int tid = threadIdx.x;
    const int ox = blockIdx.x * TX, oy = blockIdx.y * TY;
    const float b = conv_b[OC - 1];

    for (int i = tid; i < (TY + 6) * (TX + 6); i += 256) {
        int ly = i / (TX + 6), lx = i % (TX + 6);
        int gy = oy - 3 + ly, gx = ox - 3 + lx;
        float v = 0.f;                                   // zero pad for avg-sum
        if (gy >= 0 && gy < HH && gx >= 0 && gx < WW) {
            int p = gy * WW + gx;
            float raw = b;
            #pragma unroll
            for (int g = 0; g < CG; ++g) raw += partial[g * HW_ + p];
            float s = 1.f / (1.f + expf(-raw));
            v = fminf(fmaxf(s, 1e-4f), 1.f - 1e-4f);
        }
        sc[ly][lx] = v;
    }
    __syncthreads();

    for (int i = tid; i < (TY + 4) * (TX + 4); i += 256) {
        int ly = i / (TX + 4), lx = i % (TX + 4);
        int gy = oy - 2 + ly, gx = ox - 2 + lx;
        float v = -FLT_MAX;                              // -inf pad for max
        if (gy >= 0 && gy < HH && gx >= 0 && gx < WW) {
            float sum = 0.f;
            #pragma unroll
            for (int dy = 0; dy < 3; ++dy)
                #pragma unroll
                for (int dx = 0; dx < 3; ++dx)
                    sum += sc[ly + dy][lx + dx];
            v = (sc[ly + 1][lx + 1] + sum / 9.0f) * 0.5f;
        }
        s2[ly][lx] = v;
    }
    __syncthreads();

    const int tx = tid & 31, ty = tid >> 5;
    float c = s2[ty + 2][tx + 2];
    float m = -FLT_MAX;
    #pragma unroll
    for (int dy = 0; dy < 5; ++dy)
        #pragma unroll
        for (int dx = 0; dx < 5; ++dx)
            m = fmaxf(m, s2[ty + dy][tx + dx]);
    if (m == c) {                                        // survivor (c > 0 always)
        int slot = atomicAdd(counter, 1);
        if (slot < CAP) {
            cand_val[slot] = c;
            cand_idx[slot] = (oy + ty) * WW + (ox + tx);
        }
    }
}

// ---------------------------------------------------------------------------
// K3: wave-bitonic top-30 (u64 key = value-desc, index-asc tie-break; exact
// lax.top_k semantics; order-invariant to atomic append order).
// ---------------------------------------------------------------------------
__device__ __forceinline__ unsigned long long bsort64(unsigned long long key,
                                                      int lane) {
    #pragma unroll
    for (int k = 2; k <= 64; k <<= 1) {
        #pragma unroll
        for (int j = k >> 1; j > 0; j >>= 1) {
            unsigned long long o = __shfl_xor(key, j);
            bool lower = (lane & j) == 0;
            bool asc   = (lane & k) == 0;
            unsigned long long mn = key < o ? key : o;
            unsigned long long mx = key < o ? o : key;
            key = (lower == asc) ? mn : mx;
        }
    }
    return key;   // ascending across lanes
}

__device__ __forceinline__ unsigned long long bmerge64(unsigned long long key,
                                                       int lane) {
    #pragma unroll
    for (int j = 32; j > 0; j >>= 1) {
        unsigned long long o = __shfl_xor(key, j);
        bool lower = (lane & j) == 0;
        unsigned long long mn = key < o ? key : o;
        unsigned long long mx = key < o ? o : key;
        key = lower ? mn : mx;
    }
    return key;   // sorts a bitonic sequence ascending
}

__global__ __launch_bounds__(512) void k_select(const float* __restrict__ cand_val,
                                                const int* __restrict__ cand_idx,
                                                const int* __restrict__ counter,
                                                float* __restrict__ out,
                                                int* __restrict__ selpix) {
    __shared__ unsigned long long lk[512];
    const int tid = threadIdx.x;
    const int lane = tid & 63, wv = tid >> 6;
    int n = *counter; if (n > CAP) n = CAP;

    unsigned long long R = 0;   // all-zero list is trivially sorted ascending
    for (int base = wv * 64; base < n; base += 512) {
        int j = base + lane;
        unsigned long long key = 0;
        if (j < n) {
            unsigned fb = __float_as_uint(cand_val[j]);   // value>0 -> fb>0
            key = ((unsigned long long)fb << 32)
                | (unsigned long long)(0xFFFFFFFFu - (unsigned)cand_idx[j]);
        }
        key = bsort64(key, lane);                 // chunk ascending
        unsigned long long crev = __shfl_xor(key, 63);    // chunk descending
        R = R > crev ? R : crev;                  // top-64 of union (bitonic)
        R = bmerge64(R, lane);                    // re-sort ascending
    }
    lk[tid] = R;
    __syncthreads();

    if (wv == 0) {
        R = lk[lane];
        #pragma unroll
        for (int w = 1; w < 8; ++w) {
            unsigned long long c = lk[w * 64 + lane];
            unsigned long long crev = __shfl_xor(c, 63);
            R = R > crev ? R : crev;
            R = bmerge64(R, lane);
        }
        int r = 63 - lane;                        // rank r lives at lane 63-r
        if (r < NPROP) {
            float s = 0.f; int p = 0;
            if (R != 0) {
                s = __uint_as_float((unsigned)(R >> 32));
                p = (int)(0xFFFFFFFFu - (unsigned)(R & 0xFFFFFFFFu));
            }
            out[2 * r]     = (float)(p >> 8);     // y
            out[2 * r + 1] = (float)(p & 255);    // x
            out[60 + r] = s;                      // score
            out[60 + NPROP + NPROP * IC + r] = (s > 0.01f) ? 1.f : 0.f;  // valid
            selpix[r] = p;
        }
    }
}

// ---------------------------------------------------------------------------
// K4: gather instance_param in (480, 30) layout: out[90 + c*30 + i] = f[c, p_i]
// ---------------------------------------------------------------------------
__global__ __launch_bounds__(256) void k_gather(const float* __restrict__ f,
                                                const int* __restrict__ selpix,
                                                float* __restrict__ out) {
    __shared__ int sp[NPROP];
    const int tid = threadIdx.x;
    if (tid < NPROP) sp[tid] = selpix[tid];
    __syncthreads();
    int idx = blockIdx.x * 256 + tid;                 // 0 .. 14399
    if (idx < IC * NPROP) {
        int c = idx / NPROP, i = idx % NPROP;
        out[60 + NPROP + idx] = f[(size_t)c * HW_ + sp[i]];
    }
}

extern "C" void kernel_launch(void* const* d_in, const int* in_sizes, int n_in,
                              void* d_out, int out_size, void* d_ws, size_t ws_size,
                              hipStream_t stream) {
    const float* features = (const float*)d_in[0];
    const float* conv_w   = (const float*)d_in[1];
    const float* conv_b   = (const float*)d_in[2];
    float* out = (float*)d_out;
    char* ws = (char*)d_ws;

    // ws layout (~2.05 MB total)
    float* partial  = (float*)ws;                               // 8*65536*4 = 2 MB
    float* cand_val = (float*)(ws + (2 << 20));                 // 24 KB
    int*   cand_idx = (int*)  (ws + (2 << 20) + CAP * 4);       // 24 KB
    int*   counter  = (int*)  (ws + (2 << 20) + CAP * 8);       // 4 B
    int*   selpix   = (int*)  (ws + (2 << 20) + CAP * 8 + 16);  // 120 B

    k_dot   <<<dim3(HW_ / 1024, CG), 256, 0, stream>>>(features, conv_w,
                                                       partial, counter);
    k_pool  <<<dim3(WW / 32, HH / 8), 256, 0, stream>>>(partial, conv_b,
                                                        cand_val, cand_idx, counter);
    k_select<<<1, 512, 0, stream>>>(cand_val, cand_idx, counter, out, selpix);
    k_gather<<<(IC * NPROP + 255) / 256, 256, 0, stream>>>(features, selpix, out);
}